// Round 2
// baseline (573.959 us; speedup 1.0000x reference)
//
#include <hip/hip_runtime.h>
#include <hip/hip_bf16.h>

#define N_NODES 4096
#define FEAT    255
#define NB      8
#define NT      16384
#define NG      4

typedef __attribute__((ext_vector_type(8))) short          short8;
typedef __attribute__((ext_vector_type(8))) __bf16         bf16x8;
typedef __attribute__((ext_vector_type(4))) float          f32x4;
typedef __attribute__((ext_vector_type(4))) unsigned short ushort4v;

__device__ __forceinline__ unsigned short f2bf(float f) {
  unsigned int u = __builtin_bit_cast(unsigned int, f);
  u += 0x7fffu + ((u >> 16) & 1u);           // RNE (inputs are finite)
  return (unsigned short)(u >> 16);
}

__device__ __forceinline__ f32x4 mfma16(short8 a, short8 b, f32x4 c) {
  return __builtin_amdgcn_mfma_f32_16x16x32_bf16(
      __builtin_bit_cast(bf16x8, a), __builtin_bit_cast(bf16x8, b), c, 0, 0, 0);
}

// async global->LDS, 16B per lane; lds dest must be wave-uniform base (HW adds lane*16)
__device__ __forceinline__ void gload_lds16(const void* g, void* l) {
  __builtin_amdgcn_global_load_lds((__attribute__((address_space(1))) void*)(void*)g,
                                   (__attribute__((address_space(3))) void*)l, 16, 0, 0);
}

// ---------------------------------------------------------------- deg + bf16 cvt
__global__ __launch_bounds__(256)
void deg_cvt(const float* __restrict__ adj, unsigned short* __restrict__ adjbf,
             float* __restrict__ deg)
{
  const int n = blockIdx.x;
  const int tid = threadIdx.x;
  const float* row = adj + (size_t)n * N_NODES;
  float s = 0.f;
#pragma unroll
  for (int it = 0; it < 4; ++it) {
    int idx = it * 1024 + tid * 4;
    float4 v = *(const float4*)(row + idx);
    s += (v.x + v.y) + (v.z + v.w);
    ushort4v o;
    o[0] = f2bf(v.x); o[1] = f2bf(v.y); o[2] = f2bf(v.z); o[3] = f2bf(v.w);
    *(ushort4v*)(adjbf + (size_t)n * N_NODES + idx) = o;
  }
#pragma unroll
  for (int off = 32; off > 0; off >>= 1) s += __shfl_xor(s, off);
  __shared__ float ws4[4];
  if ((tid & 63) == 0) ws4[tid >> 6] = s;
  __syncthreads();
  if (tid == 0) deg[n] = (ws4[0] + ws4[1]) + (ws4[2] + ws4[3]);
}

// ---------------------------------------------------------------- top-8 (tie: lower idx)
__global__ __launch_bounds__(256)
void topk_kernel(const float* __restrict__ deg, int* __restrict__ brk)
{
  __shared__ float v[N_NODES];
  __shared__ float bv[256];
  __shared__ int   bi[256];
  const int tid = threadIdx.x;
  for (int i = tid; i < N_NODES; i += 256) v[i] = deg[i];
  __syncthreads();
  for (int it = 0; it < NB; ++it) {
    float best = -1e30f; int bidx = 0x7fffffff;
    for (int i = tid; i < N_NODES; i += 256) {
      float x = v[i];
      if (x > best) { best = x; bidx = i; }
    }
    bv[tid] = best; bi[tid] = bidx;
    __syncthreads();
    if (tid == 0) {
      float bb = -1e30f; int bbi = 0x7fffffff;
      for (int i = 0; i < 256; ++i) {
        if (bv[i] > bb || (bv[i] == bb && bi[i] < bbi)) { bb = bv[i]; bbi = bi[i]; }
      }
      brk[it] = bbi;
      v[bbi] = -1e30f;
    }
    __syncthreads();
  }
}

// ---------------------------------------------------------------- adj columns at brk
__global__ __launch_bounds__(256)
void extract_cols(const float* __restrict__ adj, const int* __restrict__ brk,
                  float* __restrict__ adjcol)
{
  const int n = blockIdx.x * 256 + threadIdx.x;
#pragma unroll
  for (int b = 0; b < NB; ++b)
    adjcol[b * N_NODES + n] = adj[(size_t)n * N_NODES + brk[b]];
}

// ---------------------------------------------------------------- Yt[d][m] = (X @ W1[:255])^T  bf16
__global__ __launch_bounds__(256)
void gemm0(const float* __restrict__ X, const float* __restrict__ W1,
           unsigned short* __restrict__ Yt)
{
  __shared__ float xr[FEAT];
  const int m = blockIdx.x;
  const int d = threadIdx.x;
  if (d < FEAT) xr[d] = X[(size_t)m * FEAT + d];
  __syncthreads();
  float s = 0.f;
#pragma unroll 5
  for (int f = 0; f < FEAT; ++f) s += xr[f] * W1[f * 256 + d];
  Yt[(size_t)d * N_NODES + m] = f2bf(s);
}

// ---------------------------------------------------------------- W2t[d][k] bf16
__global__ __launch_bounds__(256)
void w2t_kernel(const float* __restrict__ W2, unsigned short* __restrict__ W2t)
{
  const int k = blockIdx.x, d = threadIdx.x;
  W2t[(size_t)d * 256 + k] = f2bf(W2[(size_t)k * 256 + d]);
}

// ---------------------------------------------------------------- bf16 GEMM, C = A @ Bt^T
// A: [M][K] bf16 row-major, Bt: [N][K] bf16 row-major, C: [M][N] fp32.
// m97 structure: 2x2 wave grid, FMxFN 16x16x32 frags per wave, BK=64, global_load_lds w16.
template<int BM, int BN, int BK, int FM, int FN>
__global__ __launch_bounds__(256)
void gemm_bt(const unsigned short* __restrict__ A, const unsigned short* __restrict__ Bt,
             float* __restrict__ C, int M, int Nn, int K)
{
  static_assert(BK == 64, "staging math assumes BK=64");
  __shared__ unsigned short As[BM * BK];
  __shared__ unsigned short Bs[BN * BK];
  const int tid  = threadIdx.x;
  const int lane = tid & 63;
  const int w    = tid >> 6;
  const int wr   = w >> 1, wc = w & 1;
  const int lhi  = lane >> 4, llo = lane & 15;
  const int brow = blockIdx.x * BM;
  const int bcol = blockIdx.y * BN;

  f32x4 acc[FM][FN];
  const f32x4 z = {0.f, 0.f, 0.f, 0.f};
#pragma unroll
  for (int m = 0; m < FM; ++m)
#pragma unroll
    for (int n = 0; n < FN; ++n) acc[m][n] = z;

  for (int k0 = 0; k0 < K; k0 += BK) {
    __syncthreads();
#pragma unroll
    for (int i = 0; i < (BM * BK * 2) / 4096; ++i) {
      int byte = i * 4096 + tid * 16;
      int row  = byte / (BK * 2);
      int kb   = byte % (BK * 2);
      gload_lds16(A + (size_t)(brow + row) * K + k0 + (kb >> 1),
                  As + ((i * 4096 + w * 1024) >> 1));
    }
#pragma unroll
    for (int i = 0; i < (BN * BK * 2) / 4096; ++i) {
      int byte = i * 4096 + tid * 16;
      int row  = byte / (BK * 2);
      int kb   = byte % (BK * 2);
      gload_lds16(Bt + (size_t)(bcol + row) * K + k0 + (kb >> 1),
                  Bs + ((i * 4096 + w * 1024) >> 1));
    }
    __syncthreads();
#pragma unroll
    for (int kk = 0; kk < BK; kk += 32) {
      short8 fa[FM], fb[FN];
#pragma unroll
      for (int m = 0; m < FM; ++m)
        fa[m] = *(const short8*)&As[(wr * FM * 16 + m * 16 + llo) * BK + kk + lhi * 8];
#pragma unroll
      for (int n = 0; n < FN; ++n)
        fb[n] = *(const short8*)&Bs[(wc * FN * 16 + n * 16 + llo) * BK + kk + lhi * 8];
#pragma unroll
      for (int m = 0; m < FM; ++m)
#pragma unroll
        for (int n = 0; n < FN; ++n)
          acc[m][n] = mfma16(fa[m], fb[n], acc[m][n]);
    }
  }
#pragma unroll
  for (int m = 0; m < FM; ++m)
#pragma unroll
    for (int n = 0; n < FN; ++n) {
      const int r = brow + wr * FM * 16 + m * 16 + lhi * 4;
      const int c = bcol + wc * FN * 16 + n * 16 + llo;
      float* cp = C + (size_t)r * Nn + c;
#pragma unroll
      for (int i = 0; i < 4; ++i) cp[(size_t)i * Nn] = acc[m][n][i];
    }
}

// ---------------------------------------------------------------- Ht[b*256+d][m] = bf16(relu(base+b1+adjcol*W1last))
__global__ __launch_bounds__(256)
void h_kernel(const float* __restrict__ base, const float* __restrict__ adjcol,
              const float* __restrict__ b1, const float* __restrict__ W1,
              unsigned short* __restrict__ Ht)
{
  __shared__ float bs[32][261];              // pad 261: conflict-free column reads
  const int tid = threadIdx.x;
  const int m0  = blockIdx.x * 32;
  const int b   = blockIdx.y;
#pragma unroll
  for (int it = 0; it < 8; ++it) {
    int lin = it * 1024 + tid * 4;
    int mm = lin >> 8, d = lin & 255;
    float4 v = *(const float4*)(base + (size_t)(m0 + mm) * 256 + d);
    bs[mm][d] = v.x; bs[mm][d + 1] = v.y; bs[mm][d + 2] = v.z; bs[mm][d + 3] = v.w;
  }
  __syncthreads();
  const int ml = tid & 31, dg = tid >> 5;
  const float ac = adjcol[b * N_NODES + m0 + ml];
  const float* w1l = W1 + 255 * 256;
#pragma unroll 4
  for (int dd = 0; dd < 32; ++dd) {
    int d = dg * 32 + dd;
    float v = bs[ml][d] + b1[d] + ac * w1l[d];
    v = fmaxf(v, 0.f);
    Ht[(size_t)(b * 256 + d) * N_NODES + m0 + ml] = f2bf(v);
  }
}

// ---------------------------------------------------------------- out = Mcat@W2 + b2, fused layernorm -> holo fp32
__global__ __launch_bounds__(256)
void gemm3_ln(const float* __restrict__ Mcat, const unsigned short* __restrict__ W2t,
              const float* __restrict__ b2, const float* __restrict__ gamma,
              const float* __restrict__ beta, float* __restrict__ holo)
{
  const int tid  = threadIdx.x;
  const int w    = tid >> 6, lane = tid & 63;
  const int lhi  = lane >> 4, llo = lane & 15;
  const int n0   = blockIdx.x * 64;
  const int b    = blockIdx.y;
  const int row0 = n0 + w * 16;

  f32x4 acc[16];
  const f32x4 z = {0.f, 0.f, 0.f, 0.f};
#pragma unroll
  for (int j = 0; j < 16; ++j) acc[j] = z;

  const float* arow = Mcat + (size_t)(row0 + llo) * 2048 + b * 256;
#pragma unroll
  for (int k0 = 0; k0 < 256; k0 += 32) {
    const float4 a0 = *(const float4*)(arow + k0 + lhi * 8);
    const float4 a1 = *(const float4*)(arow + k0 + lhi * 8 + 4);
    float av[8] = {a0.x, a0.y, a0.z, a0.w, a1.x, a1.y, a1.z, a1.w};
    short8 fa;
#pragma unroll
    for (int i = 0; i < 8; ++i) fa[i] = (short)f2bf(av[i]);
#pragma unroll
    for (int j = 0; j < 16; ++j) {
      const short8 fb = *(const short8*)&W2t[(size_t)(j * 16 + llo) * 256 + k0 + lhi * 8];
      acc[j] = mfma16(fa, fb, acc[j]);
    }
  }
  float b2v[16];
#pragma unroll
  for (int j = 0; j < 16; ++j) b2v[j] = b2[j * 16 + llo];

  float mu[4], rs[4];
#pragma unroll
  for (int i = 0; i < 4; ++i) {
    float s = 0.f;
#pragma unroll
    for (int j = 0; j < 16; ++j) s += acc[j][i] + b2v[j];
    s += __shfl_xor(s, 1); s += __shfl_xor(s, 2);
    s += __shfl_xor(s, 4); s += __shfl_xor(s, 8);
    mu[i] = s * (1.f / 256.f);
  }
#pragma unroll
  for (int i = 0; i < 4; ++i) {
    float q = 0.f;
#pragma unroll
    for (int j = 0; j < 16; ++j) { float d = acc[j][i] + b2v[j] - mu[i]; q += d * d; }
    q += __shfl_xor(q, 1); q += __shfl_xor(q, 2);
    q += __shfl_xor(q, 4); q += __shfl_xor(q, 8);
    rs[i] = rsqrtf(q * (1.f / 256.f) + 1e-5f);
  }
  float* hb = holo + ((size_t)b * N_NODES + row0 + lhi * 4) * 256 + llo;
#pragma unroll
  for (int j = 0; j < 16; ++j) {
    const float gv = gamma[j * 16 + llo];
    const float bt = beta[j * 16 + llo];
#pragma unroll
    for (int i = 0; i < 4; ++i) {
      float x = acc[j][i] + b2v[j];
      hb[(size_t)i * 256 + j * 16] = (x - mu[i]) * rs[i] * gv + bt;
    }
  }
}

// ---------------------------------------------------------------- gather + product + group mean
__global__ __launch_bounds__(256)
void gather_k(const float* __restrict__ holo, const int* __restrict__ tc,
              const int* __restrict__ gidx, float* __restrict__ out)
{
  const int t = blockIdx.x;
  const int d = threadIdx.x;
  const int i = tc[t];
  const int j = tc[NT + t];
  float a0 = 0.f, a1 = 0.f, a2 = 0.f, a3 = 0.f;
  float c0 = 0.f, c1 = 0.f, c2 = 0.f, c3 = 0.f;
#pragma unroll
  for (int b = 0; b < NB; ++b) {
    const int g = gidx[b];
    const float p = holo[((size_t)b * N_NODES + i) * 256 + d] *
                    holo[((size_t)b * N_NODES + j) * 256 + d];
    a0 += (g == 0) ? p : 0.f;  c0 += (g == 0) ? 1.f : 0.f;
    a1 += (g == 1) ? p : 0.f;  c1 += (g == 1) ? 1.f : 0.f;
    a2 += (g == 2) ? p : 0.f;  c2 += (g == 2) ? 1.f : 0.f;
    a3 += (g == 3) ? p : 0.f;  c3 += (g == 3) ? 1.f : 0.f;
  }
  float* ob = out + (size_t)t * 1024 + d;
  ob[0]   = a0 / fmaxf(c0, 1.f);
  ob[256] = a1 / fmaxf(c1, 1.f);
  ob[512] = a2 / fmaxf(c2, 1.f);
  ob[768] = a3 / fmaxf(c3, 1.f);
}

// ----------------------------------------------------------------
extern "C" void kernel_launch(void* const* d_in, const int* in_sizes, int n_in,
                              void* d_out, int out_size, void* d_ws, size_t ws_size,
                              hipStream_t stream)
{
  const float* X     = (const float*)d_in[0];
  const float* adj   = (const float*)d_in[1];
  const float* W1    = (const float*)d_in[2];
  const float* b1    = (const float*)d_in[3];
  const float* W2    = (const float*)d_in[4];
  const float* b2    = (const float*)d_in[5];
  const float* gamma = (const float*)d_in[6];
  const float* beta  = (const float*)d_in[7];
  const int*   tc    = (const int*)d_in[8];
  const int*   gidx  = (const int*)d_in[9];

  char* w = (char*)d_ws;
  size_t off = 0;
  unsigned short* adjbf = (unsigned short*)(w + off);            // 32 MB, dead after gemm2
  float*          holo  = (float*)(w + off);  off += 33554432;   // reuses adjbf region
  unsigned short* Ht    = (unsigned short*)(w + off); off += 16777216;
  float*          Mcat  = (float*)(w + off);  off += 33554432;
  float*          base  = (float*)(w + off);  off += 4194304;
  unsigned short* Yt    = (unsigned short*)(w + off); off += 2097152;
  float*          deg   = (float*)(w + off);  off += 16384;
  int*            brk   = (int*)(w + off);    off += 256;
  float*          adjcol= (float*)(w + off);  off += 131072;
  unsigned short* W2t   = (unsigned short*)(w + off); off += 131072;
  float* out = (float*)d_out;

  deg_cvt     <<<N_NODES, 256, 0, stream>>>(adj, adjbf, deg);
  topk_kernel <<<1, 256, 0, stream>>>(deg, brk);
  extract_cols<<<N_NODES / 256, 256, 0, stream>>>(adj, brk, adjcol);
  gemm0       <<<N_NODES, 256, 0, stream>>>(X, W1, Yt);
  w2t_kernel  <<<256, 256, 0, stream>>>(W2, W2t);
  gemm_bt<64, 64, 64, 2, 2>  <<<dim3(N_NODES / 64, 256 / 64), 256, 0, stream>>>(
      adjbf, Yt, base, N_NODES, 256, N_NODES);
  h_kernel    <<<dim3(N_NODES / 32, NB), 256, 0, stream>>>(base, adjcol, b1, W1, Ht);
  gemm_bt<128, 128, 64, 4, 4><<<dim3(N_NODES / 128, 2048 / 128), 256, 0, stream>>>(
      adjbf, Ht, Mcat, N_NODES, 2048, N_NODES);
  gemm3_ln    <<<dim3(N_NODES / 64, NB), 256, 0, stream>>>(Mcat, W2t, b2, gamma, beta, holo);
  gather_k    <<<NT, 256, 0, stream>>>(holo, tc, gidx, out);
}

// Round 5
// 436.083 us; speedup vs baseline: 1.3162x; 1.3162x over previous
//
#include <hip/hip_runtime.h>
#include <hip/hip_bf16.h>

#define N_NODES 4096
#define FEAT    255
#define NB      8
#define NT      16384
#define NG      4

typedef __attribute__((ext_vector_type(8))) short          short8;
typedef __attribute__((ext_vector_type(8))) __bf16         bf16x8;
typedef __attribute__((ext_vector_type(4))) float          f32x4;
typedef __attribute__((ext_vector_type(4))) unsigned short ushort4v;

__device__ __forceinline__ unsigned short f2bf(float f) {
  unsigned int u = __builtin_bit_cast(unsigned int, f);
  u += 0x7fffu + ((u >> 16) & 1u);           // RNE (inputs are finite)
  return (unsigned short)(u >> 16);
}

__device__ __forceinline__ f32x4 mfma16(short8 a, short8 b, f32x4 c) {
  return __builtin_amdgcn_mfma_f32_16x16x32_bf16(
      __builtin_bit_cast(bf16x8, a), __builtin_bit_cast(bf16x8, b), c, 0, 0, 0);
}

// async global->LDS, 16B per lane; lds dest must be wave-uniform base (HW adds lane*16)
__device__ __forceinline__ void gload_lds16(const void* g, void* l) {
  __builtin_amdgcn_global_load_lds((__attribute__((address_space(1))) void*)(void*)g,
                                   (__attribute__((address_space(3))) void*)l, 16, 0, 0);
}

// ---------------------------------------------------------------- deg + bf16 cvt
__global__ __launch_bounds__(256)
void deg_cvt(const float* __restrict__ adj, unsigned short* __restrict__ adjbf,
             float* __restrict__ deg)
{
  const int n = blockIdx.x;
  const int tid = threadIdx.x;
  const float* row = adj + (size_t)n * N_NODES;
  float s = 0.f;
#pragma unroll
  for (int it = 0; it < 4; ++it) {
    int idx = it * 1024 + tid * 4;
    float4 v = *(const float4*)(row + idx);
    s += (v.x + v.y) + (v.z + v.w);
    ushort4v o;
    o[0] = f2bf(v.x); o[1] = f2bf(v.y); o[2] = f2bf(v.z); o[3] = f2bf(v.w);
    *(ushort4v*)(adjbf + (size_t)n * N_NODES + idx) = o;
  }
#pragma unroll
  for (int off = 32; off > 0; off >>= 1) s += __shfl_xor(s, off);
  __shared__ float ws4[4];
  if ((tid & 63) == 0) ws4[tid >> 6] = s;
  __syncthreads();
  if (tid == 0) deg[n] = (ws4[0] + ws4[1]) + (ws4[2] + ws4[3]);
}

// ---------------------------------------------------------------- top-8 (tie: lower idx)
// wave-parallel argmax: 16 strided LDS reads/thread -> 64-lane shfl_xor butterfly
// (val desc, idx asc) -> 4-way cross-wave combine. Replaces the tid==0 serial
// 256-scan that cost 161 us (8*256 LDS-latency-bound serial iterations).
__global__ __launch_bounds__(256)
void topk_kernel(const float* __restrict__ deg, int* __restrict__ brk)
{
  __shared__ float v[N_NODES];
  __shared__ float wv[4];
  __shared__ int   wi[4];
  const int tid = threadIdx.x;
  for (int i = tid; i < N_NODES; i += 256) v[i] = deg[i];
  __syncthreads();
  for (int it = 0; it < NB; ++it) {
    float best = -1e30f; int bidx = 0x7fffffff;
#pragma unroll
    for (int k = 0; k < N_NODES / 256; ++k) {
      int i = k * 256 + tid;
      float x = v[i];
      if (x > best) { best = x; bidx = i; }   // ascending scan: ties keep lower idx
    }
#pragma unroll
    for (int off = 1; off < 64; off <<= 1) {
      float ov = __shfl_xor(best, off);
      int   oi = __shfl_xor(bidx, off);
      if (ov > best || (ov == best && oi < bidx)) { best = ov; bidx = oi; }
    }
    if ((tid & 63) == 0) { wv[tid >> 6] = best; wi[tid >> 6] = bidx; }
    __syncthreads();
    if (tid == 0) {
      float bb = wv[0]; int bbi = wi[0];
#pragma unroll
      for (int k = 1; k < 4; ++k)
        if (wv[k] > bb || (wv[k] == bb && wi[k] < bbi)) { bb = wv[k]; bbi = wi[k]; }
      brk[it] = bbi;
      v[bbi] = -1e30f;
    }
    __syncthreads();
  }
}

// ---------------------------------------------------------------- adj columns at brk
__global__ __launch_bounds__(256)
void extract_cols(const float* __restrict__ adj, const int* __restrict__ brk,
                  float* __restrict__ adjcol)
{
  const int n = blockIdx.x * 256 + threadIdx.x;
#pragma unroll
  for (int b = 0; b < NB; ++b)
    adjcol[b * N_NODES + n] = adj[(size_t)n * N_NODES + brk[b]];
}

// ---------------------------------------------------------------- Yt[d][m] = (X @ W1[:255])^T  bf16
__global__ __launch_bounds__(256)
void gemm0(const float* __restrict__ X, const float* __restrict__ W1,
           unsigned short* __restrict__ Yt)
{
  __shared__ float xr[FEAT];
  const int m = blockIdx.x;
  const int d = threadIdx.x;
  if (d < FEAT) xr[d] = X[(size_t)m * FEAT + d];
  __syncthreads();
  float s = 0.f;
#pragma unroll 5
  for (int f = 0; f < FEAT; ++f) s += xr[f] * W1[f * 256 + d];
  Yt[(size_t)d * N_NODES + m] = f2bf(s);
}

// ---------------------------------------------------------------- W2t[d][k] bf16
__global__ __launch_bounds__(256)
void w2t_kernel(const float* __restrict__ W2, unsigned short* __restrict__ W2t)
{
  const int k = blockIdx.x, d = threadIdx.x;
  W2t[(size_t)d * 256 + k] = f2bf(W2[(size_t)k * 256 + d]);
}

// ---------------------------------------------------------------- bf16 GEMM, C = A @ Bt^T
// A: [M][K] bf16 row-major, Bt: [N][K] bf16 row-major, C: [M][N] fp32.
// m97 structure: 2x2 wave grid, FMxFN 16x16x32 frags per wave, BK=64, global_load_lds w16.
template<int BM, int BN, int BK, int FM, int FN>
__global__ __launch_bounds__(256)
void gemm_bt(const unsigned short* __restrict__ A, const unsigned short* __restrict__ Bt,
             float* __restrict__ C, int M, int Nn, int K)
{
  static_assert(BK == 64, "staging math assumes BK=64");
  __shared__ unsigned short As[BM * BK];
  __shared__ unsigned short Bs[BN * BK];
  const int tid  = threadIdx.x;
  const int lane = tid & 63;
  const int w    = tid >> 6;
  const int wr   = w >> 1, wc = w & 1;
  const int lhi  = lane >> 4, llo = lane & 15;
  const int brow = blockIdx.x * BM;
  const int bcol = blockIdx.y * BN;

  f32x4 acc[FM][FN];
  const f32x4 z = {0.f, 0.f, 0.f, 0.f};
#pragma unroll
  for (int m = 0; m < FM; ++m)
#pragma unroll
    for (int n = 0; n < FN; ++n) acc[m][n] = z;

  for (int k0 = 0; k0 < K; k0 += BK) {
    __syncthreads();
#pragma unroll
    for (int i = 0; i < (BM * BK * 2) / 4096; ++i) {
      int byte = i * 4096 + tid * 16;
      int row  = byte / (BK * 2);
      int kb   = byte % (BK * 2);
      gload_lds16(A + (size_t)(brow + row) * K + k0 + (kb >> 1),
                  As + ((i * 4096 + w * 1024) >> 1));
    }
#pragma unroll
    for (int i = 0; i < (BN * BK * 2) / 4096; ++i) {
      int byte = i * 4096 + tid * 16;
      int row  = byte / (BK * 2);
      int kb   = byte % (BK * 2);
      gload_lds16(Bt + (size_t)(bcol + row) * K + k0 + (kb >> 1),
                  Bs + ((i * 4096 + w * 1024) >> 1));
    }
    __syncthreads();
#pragma unroll
    for (int kk = 0; kk < BK; kk += 32) {
      short8 fa[FM], fb[FN];
#pragma unroll
      for (int m = 0; m < FM; ++m)
        fa[m] = *(const short8*)&As[(wr * FM * 16 + m * 16 + llo) * BK + kk + lhi * 8];
#pragma unroll
      for (int n = 0; n < FN; ++n)
        fb[n] = *(const short8*)&Bs[(wc * FN * 16 + n * 16 + llo) * BK + kk + lhi * 8];
#pragma unroll
      for (int m = 0; m < FM; ++m)
#pragma unroll
        for (int n = 0; n < FN; ++n)
          acc[m][n] = mfma16(fa[m], fb[n], acc[m][n]);
    }
  }
#pragma unroll
  for (int m = 0; m < FM; ++m)
#pragma unroll
    for (int n = 0; n < FN; ++n) {
      const int r = brow + wr * FM * 16 + m * 16 + lhi * 4;
      const int c = bcol + wc * FN * 16 + n * 16 + llo;
      float* cp = C + (size_t)r * Nn + c;
#pragma unroll
      for (int i = 0; i < 4; ++i) cp[(size_t)i * Nn] = acc[m][n][i];
    }
}

// ---------------------------------------------------------------- Ht[b*256+d][m] = bf16(relu(base+b1+adjcol*W1last))
__global__ __launch_bounds__(256)
void h_kernel(const float* __restrict__ base, const float* __restrict__ adjcol,
              const float* __restrict__ b1, const float* __restrict__ W1,
              unsigned short* __restrict__ Ht)
{
  __shared__ float bs[32][261];              // pad 261: conflict-free column reads
  const int tid = threadIdx.x;
  const int m0  = blockIdx.x * 32;
  const int b   = blockIdx.y;
#pragma unroll
  for (int it = 0; it < 8; ++it) {
    int lin = it * 1024 + tid * 4;
    int mm = lin >> 8, d = lin & 255;
    float4 v = *(const float4*)(base + (size_t)(m0 + mm) * 256 + d);
    bs[mm][d] = v.x; bs[mm][d + 1] = v.y; bs[mm][d + 2] = v.z; bs[mm][d + 3] = v.w;
  }
  __syncthreads();
  const int ml = tid & 31, dg = tid >> 5;
  const float ac = adjcol[b * N_NODES + m0 + ml];
  const float* w1l = W1 + 255 * 256;
#pragma unroll 4
  for (int dd = 0; dd < 32; ++dd) {
    int d = dg * 32 + dd;
    float v = bs[ml][d] + b1[d] + ac * w1l[d];
    v = fmaxf(v, 0.f);
    Ht[(size_t)(b * 256 + d) * N_NODES + m0 + ml] = f2bf(v);
  }
}

// ---------------------------------------------------------------- out = Mcat@W2 + b2, fused layernorm -> holo fp32
__global__ __launch_bounds__(256)
void gemm3_ln(const float* __restrict__ Mcat, const unsigned short* __restrict__ W2t,
              const float* __restrict__ b2, const float* __restrict__ gamma,
              const float* __restrict__ beta, float* __restrict__ holo)
{
  const int tid  = threadIdx.x;
  const int w    = tid >> 6, lane = tid & 63;
  const int lhi  = lane >> 4, llo = lane & 15;
  const int n0   = blockIdx.x * 64;
  const int b    = blockIdx.y;
  const int row0 = n0 + w * 16;

  f32x4 acc[16];
  const f32x4 z = {0.f, 0.f, 0.f, 0.f};
#pragma unroll
  for (int j = 0; j < 16; ++j) acc[j] = z;

  const float* arow = Mcat + (size_t)(row0 + llo) * 2048 + b * 256;
#pragma unroll
  for (int k0 = 0; k0 < 256; k0 += 32) {
    const float4 a0 = *(const float4*)(arow + k0 + lhi * 8);
    const float4 a1 = *(const float4*)(arow + k0 + lhi * 8 + 4);
    float av[8] = {a0.x, a0.y, a0.z, a0.w, a1.x, a1.y, a1.z, a1.w};
    short8 fa;
#pragma unroll
    for (int i = 0; i < 8; ++i) fa[i] = (short)f2bf(av[i]);
#pragma unroll
    for (int j = 0; j < 16; ++j) {
      const short8 fb = *(const short8*)&W2t[(size_t)(j * 16 + llo) * 256 + k0 + lhi * 8];
      acc[j] = mfma16(fa, fb, acc[j]);
    }
  }
  float b2v[16];
#pragma unroll
  for (int j = 0; j < 16; ++j) b2v[j] = b2[j * 16 + llo];

  float mu[4], rs[4];
#pragma unroll
  for (int i = 0; i < 4; ++i) {
    float s = 0.f;
#pragma unroll
    for (int j = 0; j < 16; ++j) s += acc[j][i] + b2v[j];
    s += __shfl_xor(s, 1); s += __shfl_xor(s, 2);
    s += __shfl_xor(s, 4); s += __shfl_xor(s, 8);
    mu[i] = s * (1.f / 256.f);
  }
#pragma unroll
  for (int i = 0; i < 4; ++i) {
    float q = 0.f;
#pragma unroll
    for (int j = 0; j < 16; ++j) { float d = acc[j][i] + b2v[j] - mu[i]; q += d * d; }
    q += __shfl_xor(q, 1); q += __shfl_xor(q, 2);
    q += __shfl_xor(q, 4); q += __shfl_xor(q, 8);
    rs[i] = rsqrtf(q * (1.f / 256.f) + 1e-5f);
  }
  float* hb = holo + ((size_t)b * N_NODES + row0 + lhi * 4) * 256 + llo;
#pragma unroll
  for (int j = 0; j < 16; ++j) {
    const float gv = gamma[j * 16 + llo];
    const float bt = beta[j * 16 + llo];
#pragma unroll
    for (int i = 0; i < 4; ++i) {
      float x = acc[j][i] + b2v[j];
      hb[(size_t)i * 256 + j * 16] = (x - mu[i]) * rs[i] * gv + bt;
    }
  }
}

// ---------------------------------------------------------------- gather + product + group mean
__global__ __launch_bounds__(256)
void gather_k(const float* __restrict__ holo, const int* __restrict__ tc,
              const int* __restrict__ gidx, float* __restrict__ out)
{
  const int t = blockIdx.x;
  const int d = threadIdx.x;
  const int i = tc[t];
  const int j = tc[NT + t];
  float a0 = 0.f, a1 = 0.f, a2 = 0.f, a3 = 0.f;
  float c0 = 0.f, c1 = 0.f, c2 = 0.f, c3 = 0.f;
#pragma unroll
  for (int b = 0; b < NB; ++b) {
    const int g = gidx[b];
    const float p = holo[((size_t)b * N_NODES + i) * 256 + d] *
                    holo[((size_t)b * N_NODES + j) * 256 + d];
    a0 += (g == 0) ? p : 0.f;  c0 += (g == 0) ? 1.f : 0.f;
    a1 += (g == 1) ? p : 0.f;  c1 += (g == 1) ? 1.f : 0.f;
    a2 += (g == 2) ? p : 0.f;  c2 += (g == 2) ? 1.f : 0.f;
    a3 += (g == 3) ? p : 0.f;  c3 += (g == 3) ? 1.f : 0.f;
  }
  float* ob = out + (size_t)t * 1024 + d;
  ob[0]   = a0 / fmaxf(c0, 1.f);
  ob[256] = a1 / fmaxf(c1, 1.f);
  ob[512] = a2 / fmaxf(c2, 1.f);
  ob[768] = a3 / fmaxf(c3, 1.f);
}

// ----------------------------------------------------------------
extern "C" void kernel_launch(void* const* d_in, const int* in_sizes, int n_in,
                              void* d_out, int out_size, void* d_ws, size_t ws_size,
                              hipStream_t stream)
{
  const float* X     = (const float*)d_in[0];
  const float* adj   = (const float*)d_in[1];
  const float* W1    = (const float*)d_in[2];
  const float* b1    = (const float*)d_in[3];
  const float* W2    = (const float*)d_in[4];
  const float* b2    = (const float*)d_in[5];
  const float* gamma = (const float*)d_in[6];
  const float* beta  = (const float*)d_in[7];
  const int*   tc    = (const int*)d_in[8];
  const int*   gidx  = (const int*)d_in[9];

  char* w = (char*)d_ws;
  size_t off = 0;
  unsigned short* adjbf = (unsigned short*)(w + off);            // 32 MB, dead after gemm2
  float*          holo  = (float*)(w + off);  off += 33554432;   // reuses adjbf region
  unsigned short* Ht    = (unsigned short*)(w + off); off += 16777216;
  float*          Mcat  = (float*)(w + off);  off += 33554432;
  float*          base  = (float*)(w + off);  off += 4194304;
  unsigned short* Yt    = (unsigned short*)(w + off); off += 2097152;
  float*          deg   = (float*)(w + off);  off += 16384;
  int*            brk   = (int*)(w + off);    off += 256;
  float*          adjcol= (float*)(w + off);  off += 131072;
  unsigned short* W2t   = (unsigned short*)(w + off); off += 131072;
  float* out = (float*)d_out;

  deg_cvt     <<<N_NODES, 256, 0, stream>>>(adj, adjbf, deg);
  topk_kernel <<<1, 256, 0, stream>>>(deg, brk);
  extract_cols<<<N_NODES / 256, 256, 0, stream>>>(adj, brk, adjcol);
  gemm0       <<<N_NODES, 256, 0, stream>>>(X, W1, Yt);
  w2t_kernel  <<<256, 256, 0, stream>>>(W2, W2t);
  gemm_bt<64, 64, 64, 2, 2>  <<<dim3(N_NODES / 64, 256 / 64), 256, 0, stream>>>(
      adjbf, Yt, base, N_NODES, 256, N_NODES);
  h_kernel    <<<dim3(N_NODES / 32, NB), 256, 0, stream>>>(base, adjcol, b1, W1, Ht);
  gemm_bt<128, 128, 64, 4, 4><<<dim3(N_NODES / 128, 2048 / 128), 256, 0, stream>>>(
      adjbf, Ht, Mcat, N_NODES, 2048, N_NODES);
  gemm3_ln    <<<dim3(N_NODES / 64, NB), 256, 0, stream>>>(Mcat, W2t, b2, gamma, beta, holo);
  gather_k    <<<NT, 256, 0, stream>>>(holo, tc, gidx, out);
}

// Round 7
// 412.213 us; speedup vs baseline: 1.3924x; 1.0579x over previous
//
#include <hip/hip_runtime.h>
#include <hip/hip_bf16.h>

#define N_NODES 4096
#define FEAT    255
#define NB      8
#define NT      16384
#define NG      4

typedef __attribute__((ext_vector_type(8))) short          short8;
typedef __attribute__((ext_vector_type(8))) __bf16         bf16x8;
typedef __attribute__((ext_vector_type(4))) float          f32x4;
typedef __attribute__((ext_vector_type(4))) unsigned short ushort4v;

__device__ __forceinline__ unsigned short f2bf(float f) {
  unsigned int u = __builtin_bit_cast(unsigned int, f);
  u += 0x7fffu + ((u >> 16) & 1u);           // RNE (inputs are finite)
  return (unsigned short)(u >> 16);
}

__device__ __forceinline__ f32x4 mfma16(short8 a, short8 b, f32x4 c) {
  return __builtin_amdgcn_mfma_f32_16x16x32_bf16(
      __builtin_bit_cast(bf16x8, a), __builtin_bit_cast(bf16x8, b), c, 0, 0, 0);
}

// async global->LDS, 16B per lane; lds dest must be wave-uniform base (HW adds lane*16)
__device__ __forceinline__ void gload_lds16(const void* g, void* l) {
  __builtin_amdgcn_global_load_lds((__attribute__((address_space(1))) void*)(void*)g,
                                   (__attribute__((address_space(3))) void*)l, 16, 0, 0);
}

// ---------------------------------------------------------------- deg + bf16 cvt
__global__ __launch_bounds__(256)
void deg_cvt(const float* __restrict__ adj, unsigned short* __restrict__ adjbf,
             float* __restrict__ deg)
{
  const int n = blockIdx.x;
  const int tid = threadIdx.x;
  const float* row = adj + (size_t)n * N_NODES;
  float s = 0.f;
#pragma unroll
  for (int it = 0; it < 4; ++it) {
    int idx = it * 1024 + tid * 4;
    float4 v = *(const float4*)(row + idx);
    s += (v.x + v.y) + (v.z + v.w);
    ushort4v o;
    o[0] = f2bf(v.x); o[1] = f2bf(v.y); o[2] = f2bf(v.z); o[3] = f2bf(v.w);
    *(ushort4v*)(adjbf + (size_t)n * N_NODES + idx) = o;
  }
#pragma unroll
  for (int off = 32; off > 0; off >>= 1) s += __shfl_xor(s, off);
  __shared__ float ws4[4];
  if ((tid & 63) == 0) ws4[tid >> 6] = s;
  __syncthreads();
  if (tid == 0) deg[n] = (ws4[0] + ws4[1]) + (ws4[2] + ws4[3]);
}

// ---------------------------------------------------------------- top-8 (tie: lower idx)
// wave-parallel argmax: 16 strided LDS reads/thread -> 64-lane shfl_xor butterfly
// (val desc, idx asc) -> 4-way cross-wave combine.
__global__ __launch_bounds__(256)
void topk_kernel(const float* __restrict__ deg, int* __restrict__ brk)
{
  __shared__ float v[N_NODES];
  __shared__ float wv[4];
  __shared__ int   wi[4];
  const int tid = threadIdx.x;
  for (int i = tid; i < N_NODES; i += 256) v[i] = deg[i];
  __syncthreads();
  for (int it = 0; it < NB; ++it) {
    float best = -1e30f; int bidx = 0x7fffffff;
#pragma unroll
    for (int k = 0; k < N_NODES / 256; ++k) {
      int i = k * 256 + tid;
      float x = v[i];
      if (x > best) { best = x; bidx = i; }   // ascending scan: ties keep lower idx
    }
#pragma unroll
    for (int off = 1; off < 64; off <<= 1) {
      float ov = __shfl_xor(best, off);
      int   oi = __shfl_xor(bidx, off);
      if (ov > best || (ov == best && oi < bidx)) { best = ov; bidx = oi; }
    }
    if ((tid & 63) == 0) { wv[tid >> 6] = best; wi[tid >> 6] = bidx; }
    __syncthreads();
    if (tid == 0) {
      float bb = wv[0]; int bbi = wi[0];
#pragma unroll
      for (int k = 1; k < 4; ++k)
        if (wv[k] > bb || (wv[k] == bb && wi[k] < bbi)) { bb = wv[k]; bbi = wi[k]; }
      brk[it] = bbi;
      v[bbi] = -1e30f;
    }
    __syncthreads();
  }
}

// ---------------------------------------------------------------- adj columns at brk
__global__ __launch_bounds__(256)
void extract_cols(const float* __restrict__ adj, const int* __restrict__ brk,
                  float* __restrict__ adjcol)
{
  const int n = blockIdx.x * 256 + threadIdx.x;
#pragma unroll
  for (int b = 0; b < NB; ++b)
    adjcol[b * N_NODES + n] = adj[(size_t)n * N_NODES + brk[b]];
}

// ---------------------------------------------------------------- Yt[d][m] = (X @ W1[:255])^T  bf16
__global__ __launch_bounds__(256)
void gemm0(const float* __restrict__ X, const float* __restrict__ W1,
           unsigned short* __restrict__ Yt)
{
  __shared__ float xr[FEAT];
  const int m = blockIdx.x;
  const int d = threadIdx.x;
  if (d < FEAT) xr[d] = X[(size_t)m * FEAT + d];
  __syncthreads();
  float s = 0.f;
#pragma unroll 5
  for (int f = 0; f < FEAT; ++f) s += xr[f] * W1[f * 256 + d];
  Yt[(size_t)d * N_NODES + m] = f2bf(s);
}

// ---------------------------------------------------------------- W2t[d][k] bf16
__global__ __launch_bounds__(256)
void w2t_kernel(const float* __restrict__ W2, unsigned short* __restrict__ W2t)
{
  const int k = blockIdx.x, d = threadIdx.x;
  W2t[(size_t)d * 256 + k] = f2bf(W2[(size_t)k * 256 + d]);
}

// ---------------------------------------------------------------- bf16 GEMM, C = A @ Bt^T
// A: [M][K] bf16 row-major, Bt: [N][K] bf16 row-major, C: [M][N] fp32.
// m97 structure + T2 XOR-swizzle (16B chunks, chunk^=row&7, rule #21:
// inverse-swizzled global SOURCE in staging + same involution on ds_read).
// Fixes the 16-way bank conflict of row-stride-128B fragment reads
// (r5: SQ_LDS_BANK_CONFLICT 2.5e7, MfmaUtil 24.9%).
template<int BM, int BN, int BK, int FM, int FN>
__global__ __launch_bounds__(256)
void gemm_bt(const unsigned short* __restrict__ A, const unsigned short* __restrict__ Bt,
             float* __restrict__ C, int M, int Nn, int K)
{
  static_assert(BK == 64, "staging/swizzle math assumes BK=64 (128 B = 8 chunks/row)");
  __shared__ unsigned short As[BM * BK];
  __shared__ unsigned short Bs[BN * BK];
  const int tid  = threadIdx.x;
  const int lane = tid & 63;
  const int w    = tid >> 6;
  const int wr   = w >> 1, wc = w & 1;
  const int lhi  = lane >> 4, llo = lane & 15;
  const int brow = blockIdx.x * BM;
  const int bcol = blockIdx.y * BN;

  f32x4 acc[FM][FN];
  const f32x4 z = {0.f, 0.f, 0.f, 0.f};
#pragma unroll
  for (int m = 0; m < FM; ++m)
#pragma unroll
    for (int n = 0; n < FN; ++n) acc[m][n] = z;

  for (int k0 = 0; k0 < K; k0 += BK) {
    __syncthreads();
#pragma unroll
    for (int i = 0; i < (BM * BK * 2) / 4096; ++i) {
      int byte = i * 4096 + tid * 16;            // linear LDS byte offset
      int row  = byte >> 7;                      // 128 B per row
      int sc   = ((byte >> 4) & 7) ^ (row & 7);  // swizzled source chunk
      gload_lds16(A + (size_t)(brow + row) * K + k0 + sc * 8,
                  As + ((i * 4096 + w * 1024) >> 1));
    }
#pragma unroll
    for (int i = 0; i < (BN * BK * 2) / 4096; ++i) {
      int byte = i * 4096 + tid * 16;
      int row  = byte >> 7;
      int sc   = ((byte >> 4) & 7) ^ (row & 7);
      gload_lds16(Bt + (size_t)(bcol + row) * K + k0 + sc * 8,
                  Bs + ((i * 4096 + w * 1024) >> 1));
    }
    __syncthreads();
#pragma unroll
    for (int kk = 0; kk < BK; kk += 32) {
      short8 fa[FM], fb[FN];
#pragma unroll
      for (int m = 0; m < FM; ++m) {
        const int ar = wr * FM * 16 + m * 16 + llo;
        const int ac = ((kk >> 3) + lhi) ^ (ar & 7);   // same involution on read
        fa[m] = *(const short8*)&As[ar * BK + ac * 8];
      }
#pragma unroll
      for (int n = 0; n < FN; ++n) {
        const int br = wc * FN * 16 + n * 16 + llo;
        const int bc = ((kk >> 3) + lhi) ^ (br & 7);
        fb[n] = *(const short8*)&Bs[br * BK + bc * 8];
      }
#pragma unroll
      for (int m = 0; m < FM; ++m)
#pragma unroll
        for (int n = 0; n < FN; ++n)
          acc[m][n] = mfma16(fa[m], fb[n], acc[m][n]);
    }
  }
#pragma unroll
  for (int m = 0; m < FM; ++m)
#pragma unroll
    for (int n = 0; n < FN; ++n) {
      const int r = brow + wr * FM * 16 + m * 16 + lhi * 4;
      const int c = bcol + wc * FN * 16 + n * 16 + llo;
      float* cp = C + (size_t)r * Nn + c;
#pragma unroll
      for (int i = 0; i < 4; ++i) cp[(size_t)i * Nn] = acc[m][n][i];
    }
}

// ---------------------------------------------------------------- Ht[b*256+d][m] = bf16(relu(base+b1+adjcol*W1last))
__global__ __launch_bounds__(256)
void h_kernel(const float* __restrict__ base, const float* __restrict__ adjcol,
              const float* __restrict__ b1, const float* __restrict__ W1,
              unsigned short* __restrict__ Ht)
{
  __shared__ float bs[32][261];              // pad 261: conflict-free column reads
  const int tid = threadIdx.x;
  const int m0  = blockIdx.x * 32;
  const int b   = blockIdx.y;
#pragma unroll
  for (int it = 0; it < 8; ++it) {
    int lin = it * 1024 + tid * 4;
    int mm = lin >> 8, d = lin & 255;
    float4 v = *(const float4*)(base + (size_t)(m0 + mm) * 256 + d);
    bs[mm][d] = v.x; bs[mm][d + 1] = v.y; bs[mm][d + 2] = v.z; bs[mm][d + 3] = v.w;
  }
  __syncthreads();
  const int ml = tid & 31, dg = tid >> 5;
  const float ac = adjcol[b * N_NODES + m0 + ml];
  const float* w1l = W1 + 255 * 256;
#pragma unroll 4
  for (int dd = 0; dd < 32; ++dd) {
    int d = dg * 32 + dd;
    float v = bs[ml][d] + b1[d] + ac * w1l[d];
    v = fmaxf(v, 0.f);
    Ht[(size_t)(b * 256 + d) * N_NODES + m0 + ml] = f2bf(v);
  }
}

// ---------------------------------------------------------------- out = Mcat@W2 + b2, fused layernorm -> holo fp32
__global__ __launch_bounds__(256)
void gemm3_ln(const float* __restrict__ Mcat, const unsigned short* __restrict__ W2t,
              const float* __restrict__ b2, const float* __restrict__ gamma,
              const float* __restrict__ beta, float* __restrict__ holo)
{
  const int tid  = threadIdx.x;
  const int w    = tid >> 6, lane = tid & 63;
  const int lhi  = lane >> 4, llo = lane & 15;
  const int n0   = blockIdx.x * 64;
  const int b    = blockIdx.y;
  const int row0 = n0 + w * 16;

  f32x4 acc[16];
  const f32x4 z = {0.f, 0.f, 0.f, 0.f};
#pragma unroll
  for (int j = 0; j < 16; ++j) acc[j] = z;

  const float* arow = Mcat + (size_t)(row0 + llo) * 2048 + b * 256;
#pragma unroll
  for (int k0 = 0; k0 < 256; k0 += 32) {
    const float4 a0 = *(const float4*)(arow + k0 + lhi * 8);
    const float4 a1 = *(const float4*)(arow + k0 + lhi * 8 + 4);
    float av[8] = {a0.x, a0.y, a0.z, a0.w, a1.x, a1.y, a1.z, a1.w};
    short8 fa;
#pragma unroll
    for (int i = 0; i < 8; ++i) fa[i] = (short)f2bf(av[i]);
#pragma unroll
    for (int j = 0; j < 16; ++j) {
      const short8 fb = *(const short8*)&W2t[(size_t)(j * 16 + llo) * 256 + k0 + lhi * 8];
      acc[j] = mfma16(fa, fb, acc[j]);
    }
  }
  float b2v[16];
#pragma unroll
  for (int j = 0; j < 16; ++j) b2v[j] = b2[j * 16 + llo];

  float mu[4], rs[4];
#pragma unroll
  for (int i = 0; i < 4; ++i) {
    float s = 0.f;
#pragma unroll
    for (int j = 0; j < 16; ++j) s += acc[j][i] + b2v[j];
    s += __shfl_xor(s, 1); s += __shfl_xor(s, 2);
    s += __shfl_xor(s, 4); s += __shfl_xor(s, 8);
    mu[i] = s * (1.f / 256.f);
  }
#pragma unroll
  for (int i = 0; i < 4; ++i) {
    float q = 0.f;
#pragma unroll
    for (int j = 0; j < 16; ++j) { float d = acc[j][i] + b2v[j] - mu[i]; q += d * d; }
    q += __shfl_xor(q, 1); q += __shfl_xor(q, 2);
    q += __shfl_xor(q, 4); q += __shfl_xor(q, 8);
    rs[i] = rsqrtf(q * (1.f / 256.f) + 1e-5f);
  }
  float* hb = holo + ((size_t)b * N_NODES + row0 + lhi * 4) * 256 + llo;
#pragma unroll
  for (int j = 0; j < 16; ++j) {
    const float gv = gamma[j * 16 + llo];
    const float bt = beta[j * 16 + llo];
#pragma unroll
    for (int i = 0; i < 4; ++i) {
      float x = acc[j][i] + b2v[j];
      hb[(size_t)i * 256 + j * 16] = (x - mu[i]) * rs[i] * gv + bt;
    }
  }
}

// ---------------------------------------------------------------- gather + product + group mean
__global__ __launch_bounds__(256)
void gather_k(const float* __restrict__ holo, const int* __restrict__ tc,
              const int* __restrict__ gidx, float* __restrict__ out)
{
  const int t = blockIdx.x;
  const int d = threadIdx.x;
  const int i = tc[t];
  const int j = tc[NT + t];
  float a0 = 0.f, a1 = 0.f, a2 = 0.f, a3 = 0.f;
  float c0 = 0.f, c1 = 0.f, c2 = 0.f, c3 = 0.f;
#pragma unroll
  for (int b = 0; b < NB; ++b) {
    const int g = gidx[b];
    const float p = holo[((size_t)b * N_NODES + i) * 256 + d] *
                    holo[((size_t)b * N_NODES + j) * 256 + d];
    a0 += (g == 0) ? p : 0.f;  c0 += (g == 0) ? 1.f : 0.f;
    a1 += (g == 1) ? p : 0.f;  c1 += (g == 1) ? 1.f : 0.f;
    a2 += (g == 2) ? p : 0.f;  c2 += (g == 2) ? 1.f : 0.f;
    a3 += (g == 3) ? p : 0.f;  c3 += (g == 3) ? 1.f : 0.f;
  }
  float* ob = out + (size_t)t * 1024 + d;
  ob[0]   = a0 / fmaxf(c0, 1.f);
  ob[256] = a1 / fmaxf(c1, 1.f);
  ob[512] = a2 / fmaxf(c2, 1.f);
  ob[768] = a3 / fmaxf(c3, 1.f);
}

// ----------------------------------------------------------------
extern "C" void kernel_launch(void* const* d_in, const int* in_sizes, int n_in,
                              void* d_out, int out_size, void* d_ws, size_t ws_size,
                              hipStream_t stream)
{
  const float* X     = (const float*)d_in[0];
  const float* adj   = (const float*)d_in[1];
  const float* W1    = (const float*)d_in[2];
  const float* b1    = (const float*)d_in[3];
  const float* W2    = (const float*)d_in[4];
  const float* b2    = (const float*)d_in[5];
  const float* gamma = (const float*)d_in[6];
  const float* beta  = (const float*)d_in[7];
  const int*   tc    = (const int*)d_in[8];
  const int*   gidx  = (const int*)d_in[9];

  char* w = (char*)d_ws;
  size_t off = 0;
  unsigned short* adjbf = (unsigned short*)(w + off);            // 32 MB, dead after gemm2
  float*          holo  = (float*)(w + off);  off += 33554432;   // reuses adjbf region
  unsigned short* Ht    = (unsigned short*)(w + off); off += 16777216;
  float*          Mcat  = (float*)(w + off);  off += 33554432;
  float*          base  = (float*)(w + off);  off += 4194304;
  unsigned short* Yt    = (unsigned short*)(w + off); off += 2097152;
  float*          deg   = (float*)(w + off);  off += 16384;
  int*            brk   = (int*)(w + off);    off += 256;
  float*          adjcol= (float*)(w + off);  off += 131072;
  unsigned short* W2t   = (unsigned short*)(w + off); off += 131072;
  float* out = (float*)d_out;

  deg_cvt     <<<N_NODES, 256, 0, stream>>>(adj, adjbf, deg);
  topk_kernel <<<1, 256, 0, stream>>>(deg, brk);
  extract_cols<<<N_NODES / 256, 256, 0, stream>>>(adj, brk, adjcol);
  gemm0       <<<N_NODES, 256, 0, stream>>>(X, W1, Yt);
  w2t_kernel  <<<256, 256, 0, stream>>>(W2, W2t);
  gemm_bt<64, 64, 64, 2, 2>  <<<dim3(N_NODES / 64, 256 / 64), 256, 0, stream>>>(
      adjbf, Yt, base, N_NODES, 256, N_NODES);
  h_kernel    <<<dim3(N_NODES / 32, NB), 256, 0, stream>>>(base, adjcol, b1, W1, Ht);
  gemm_bt<128, 128, 64, 4, 4><<<dim3(N_NODES / 128, 2048 / 128), 256, 0, stream>>>(
      adjbf, Ht, Mcat, N_NODES, 2048, N_NODES);
  gemm3_ln    <<<dim3(N_NODES / 64, NB), 256, 0, stream>>>(Mcat, W2t, b2, gamma, beta, holo);
  gather_k    <<<NT, 256, 0, stream>>>(holo, tc, gidx, out);
}

// Round 9
// 374.822 us; speedup vs baseline: 1.5313x; 1.0998x over previous
//
#include <hip/hip_runtime.h>
#include <hip/hip_bf16.h>

#define N_NODES 4096
#define FEAT    255
#define NB      8
#define NT      16384
#define NG      4

typedef __attribute__((ext_vector_type(8))) short          short8;
typedef __attribute__((ext_vector_type(8))) __bf16         bf16x8;
typedef __attribute__((ext_vector_type(4))) float          f32x4;
typedef __attribute__((ext_vector_type(4))) unsigned short ushort4v;

__device__ __forceinline__ unsigned short f2bf(float f) {
  unsigned int u = __builtin_bit_cast(unsigned int, f);
  u += 0x7fffu + ((u >> 16) & 1u);           // RNE (inputs are finite)
  return (unsigned short)(u >> 16);
}

__device__ __forceinline__ f32x4 mfma16(short8 a, short8 b, f32x4 c) {
  return __builtin_amdgcn_mfma_f32_16x16x32_bf16(
      __builtin_bit_cast(bf16x8, a), __builtin_bit_cast(bf16x8, b), c, 0, 0, 0);
}

// async global->LDS, 16B per lane; lds dest must be wave-uniform base (HW adds lane*16)
__device__ __forceinline__ void gload_lds16(const void* g, void* l) {
  __builtin_amdgcn_global_load_lds((__attribute__((address_space(1))) void*)(void*)g,
                                   (__attribute__((address_space(3))) void*)l, 16, 0, 0);
}

// ---------------------------------------------------------------- deg + bf16 cvt
__global__ __launch_bounds__(256)
void deg_cvt(const float* __restrict__ adj, unsigned short* __restrict__ adjbf,
             float* __restrict__ deg)
{
  const int n = blockIdx.x;
  const int tid = threadIdx.x;
  const float* row = adj + (size_t)n * N_NODES;
  float s = 0.f;
#pragma unroll
  for (int it = 0; it < 4; ++it) {
    int idx = it * 1024 + tid * 4;
    float4 v = *(const float4*)(row + idx);
    s += (v.x + v.y) + (v.z + v.w);
    ushort4v o;
    o[0] = f2bf(v.x); o[1] = f2bf(v.y); o[2] = f2bf(v.z); o[3] = f2bf(v.w);
    *(ushort4v*)(adjbf + (size_t)n * N_NODES + idx) = o;
  }
#pragma unroll
  for (int off = 32; off > 0; off >>= 1) s += __shfl_xor(s, off);
  __shared__ float ws4[4];
  if ((tid & 63) == 0) ws4[tid >> 6] = s;
  __syncthreads();
  if (tid == 0) deg[n] = (ws4[0] + ws4[1]) + (ws4[2] + ws4[3]);
}

// ---------------------------------------------------------------- top-8 (tie: lower idx)
__global__ __launch_bounds__(256)
void topk_kernel(const float* __restrict__ deg, int* __restrict__ brk)
{
  __shared__ float v[N_NODES];
  __shared__ float wv[4];
  __shared__ int   wi[4];
  const int tid = threadIdx.x;
  for (int i = tid; i < N_NODES; i += 256) v[i] = deg[i];
  __syncthreads();
  for (int it = 0; it < NB; ++it) {
    float best = -1e30f; int bidx = 0x7fffffff;
#pragma unroll
    for (int k = 0; k < N_NODES / 256; ++k) {
      int i = k * 256 + tid;
      float x = v[i];
      if (x > best) { best = x; bidx = i; }   // ascending scan: ties keep lower idx
    }
#pragma unroll
    for (int off = 1; off < 64; off <<= 1) {
      float ov = __shfl_xor(best, off);
      int   oi = __shfl_xor(bidx, off);
      if (ov > best || (ov == best && oi < bidx)) { best = ov; bidx = oi; }
    }
    if ((tid & 63) == 0) { wv[tid >> 6] = best; wi[tid >> 6] = bidx; }
    __syncthreads();
    if (tid == 0) {
      float bb = wv[0]; int bbi = wi[0];
#pragma unroll
      for (int k = 1; k < 4; ++k)
        if (wv[k] > bb || (wv[k] == bb && wi[k] < bbi)) { bb = wv[k]; bbi = wi[k]; }
      brk[it] = bbi;
      v[bbi] = -1e30f;
    }
    __syncthreads();
  }
}

// ---------------------------------------------------------------- adj columns at brk
__global__ __launch_bounds__(256)
void extract_cols(const float* __restrict__ adj, const int* __restrict__ brk,
                  float* __restrict__ adjcol)
{
  const int n = blockIdx.x * 256 + threadIdx.x;
#pragma unroll
  for (int b = 0; b < NB; ++b)
    adjcol[b * N_NODES + n] = adj[(size_t)n * N_NODES + brk[b]];
}

// ---------------------------------------------------------------- Yt[d][m] = (X @ W1[:255])^T  bf16
// 8 rows/block (512 blocks): W1 L2 traffic 1 GB -> 134 MB vs the old
// 1-row/block version (each of 4096 blocks re-read all 261 KB of W1).
#define G0R 8
__global__ __launch_bounds__(256)
void gemm0(const float* __restrict__ X, const float* __restrict__ W1,
           unsigned short* __restrict__ Yt)
{
  __shared__ float xr[G0R][256];             // padded row stride: 16B-aligned float4 reads
  const int tid = threadIdx.x;
  const int m0  = blockIdx.x * G0R;
  for (int i = tid; i < G0R * FEAT; i += 256) {
    int r = i / FEAT, c = i - r * FEAT;
    xr[r][c] = X[(size_t)(m0 + r) * FEAT + c];
  }
  __syncthreads();
  const int d = tid;
  float s[G0R] = {};
  for (int fq = 0; fq < 252; fq += 4) {      // 63 quads; ascending f order (bit-stable)
    float w0 = W1[(fq + 0) * 256 + d];
    float w1 = W1[(fq + 1) * 256 + d];
    float w2 = W1[(fq + 2) * 256 + d];
    float w3 = W1[(fq + 3) * 256 + d];
#pragma unroll
    for (int r = 0; r < G0R; ++r) {
      float4 x4 = *(const float4*)&xr[r][fq];
      s[r] = fmaf(x4.x, w0, s[r]);
      s[r] = fmaf(x4.y, w1, s[r]);
      s[r] = fmaf(x4.z, w2, s[r]);
      s[r] = fmaf(x4.w, w3, s[r]);
    }
  }
  for (int f = 252; f < FEAT; ++f) {
    float wv = W1[f * 256 + d];
#pragma unroll
    for (int r = 0; r < G0R; ++r) s[r] = fmaf(xr[r][f], wv, s[r]);
  }
#pragma unroll
  for (int r = 0; r < G0R; ++r)
    Yt[(size_t)d * N_NODES + m0 + r] = f2bf(s[r]);
}

// ---------------------------------------------------------------- W2t[d][k] bf16
__global__ __launch_bounds__(256)
void w2t_kernel(const float* __restrict__ W2, unsigned short* __restrict__ W2t)
{
  const int k = blockIdx.x, d = threadIdx.x;
  W2t[(size_t)d * 256 + k] = f2bf(W2[(size_t)k * 256 + d]);
}

// ---------------------------------------------------------------- bf16 GEMM, C = A @ Bt^T
// A: [M][K] bf16 row-major, Bt: [N][K] bf16 row-major.
// m97 structure + T2 XOR-swizzle (verified r7: BANK_CONFLICT 2.5e7 -> 0).
// OUTBF: emit bf16 C (bit-identical to fp32 C + downstream f2bf).
// K-split via blockIdx.z: chunk kz covers K/gridDim.z, writes C + kz*M*Nn.
template<int BM, int BN, int BK, int FM, int FN, bool OUTBF>
__global__ __launch_bounds__(256)
void gemm_bt(const unsigned short* __restrict__ A, const unsigned short* __restrict__ Bt,
             void* __restrict__ Cv, int M, int Nn, int K)
{
  static_assert(BK == 64, "staging/swizzle math assumes BK=64 (128 B = 8 chunks/row)");
  __shared__ unsigned short As[BM * BK];
  __shared__ unsigned short Bs[BN * BK];
  const int tid  = threadIdx.x;
  const int lane = tid & 63;
  const int w    = tid >> 6;
  const int wr   = w >> 1, wc = w & 1;
  const int lhi  = lane >> 4, llo = lane & 15;
  const int brow = blockIdx.x * BM;
  const int bcol = blockIdx.y * BN;
  const int Kper = K / gridDim.z;
  const int kbeg = blockIdx.z * Kper;

  f32x4 acc[FM][FN];
  const f32x4 z = {0.f, 0.f, 0.f, 0.f};
#pragma unroll
  for (int m = 0; m < FM; ++m)
#pragma unroll
    for (int n = 0; n < FN; ++n) acc[m][n] = z;

  for (int k0 = kbeg; k0 < kbeg + Kper; k0 += BK) {
    __syncthreads();
#pragma unroll
    for (int i = 0; i < (BM * BK * 2) / 4096; ++i) {
      int byte = i * 4096 + tid * 16;            // linear LDS byte offset
      int row  = byte >> 7;                      // 128 B per row
      int sc   = ((byte >> 4) & 7) ^ (row & 7);  // swizzled source chunk
      gload_lds16(A + (size_t)(brow + row) * K + k0 + sc * 8,
                  As + ((i * 4096 + w * 1024) >> 1));
    }
#pragma unroll
    for (int i = 0; i < (BN * BK * 2) / 4096; ++i) {
      int byte = i * 4096 + tid * 16;
      int row  = byte >> 7;
      int sc   = ((byte >> 4) & 7) ^ (row & 7);
      gload_lds16(Bt + (size_t)(bcol + row) * K + k0 + sc * 8,
                  Bs + ((i * 4096 + w * 1024) >> 1));
    }
    __syncthreads();
#pragma unroll
    for (int kk = 0; kk < BK; kk += 32) {
      short8 fa[FM], fb[FN];
#pragma unroll
      for (int m = 0; m < FM; ++m) {
        const int ar = wr * FM * 16 + m * 16 + llo;
        const int ac = ((kk >> 3) + lhi) ^ (ar & 7);   // same involution on read
        fa[m] = *(const short8*)&As[ar * BK + ac * 8];
      }
#pragma unroll
      for (int n = 0; n < FN; ++n) {
        const int br = wc * FN * 16 + n * 16 + llo;
        const int bc = ((kk >> 3) + lhi) ^ (br & 7);
        fb[n] = *(const short8*)&Bs[br * BK + bc * 8];
      }
#pragma unroll
      for (int m = 0; m < FM; ++m)
#pragma unroll
        for (int n = 0; n < FN; ++n)
          acc[m][n] = mfma16(fa[m], fb[n], acc[m][n]);
    }
  }
#pragma unroll
  for (int m = 0; m < FM; ++m)
#pragma unroll
    for (int n = 0; n < FN; ++n) {
      const int r = brow + wr * FM * 16 + m * 16 + lhi * 4;
      const int c = bcol + wc * FN * 16 + n * 16 + llo;
      if constexpr (OUTBF) {
        unsigned short* cp = (unsigned short*)Cv + (size_t)blockIdx.z * M * Nn
                             + (size_t)r * Nn + c;
#pragma unroll
        for (int i = 0; i < 4; ++i) cp[(size_t)i * Nn] = f2bf(acc[m][n][i]);
      } else {
        float* cp = (float*)Cv + (size_t)blockIdx.z * M * Nn + (size_t)r * Nn + c;
#pragma unroll
        for (int i = 0; i < 4; ++i) cp[(size_t)i * Nn] = acc[m][n][i];
      }
    }
}

// ---------------------------------------------------------------- base = sum of 4 K-split partials
// grid must be N_NODES*256/4/256 = 1024 blocks (float4 granularity).
__global__ __launch_bounds__(256)
void reduce4(const float* __restrict__ bp, float* __restrict__ base)
{
  const size_t i = (size_t)blockIdx.x * 256 + threadIdx.x;   // float4 index
  const float4* b0 = (const float4*)bp;
  const float4* b1 = b0 + (size_t)N_NODES * 256 / 4;
  const float4* b2 = b1 + (size_t)N_NODES * 256 / 4;
  const float4* b3 = b2 + (size_t)N_NODES * 256 / 4;
  float4 v0 = b0[i], v1 = b1[i], v2 = b2[i], v3 = b3[i];
  float4 o;
  o.x = ((v0.x + v1.x) + v2.x) + v3.x;
  o.y = ((v0.y + v1.y) + v2.y) + v3.y;
  o.z = ((v0.z + v1.z) + v2.z) + v3.z;
  o.w = ((v0.w + v1.w) + v2.w) + v3.w;
  ((float4*)base)[i] = o;
}

// ---------------------------------------------------------------- Ht[b*256+d][m] = bf16(relu(base+b1+adjcol*W1last))
__global__ __launch_bounds__(256)
void h_kernel(const float* __restrict__ base, const float* __restrict__ adjcol,
              const float* __restrict__ b1, const float* __restrict__ W1,
              unsigned short* __restrict__ Ht)
{
  __shared__ float bs[32][261];              // pad 261: conflict-free column reads
  const int tid = threadIdx.x;
  const int m0  = blockIdx.x * 32;
  const int b   = blockIdx.y;
#pragma unroll
  for (int it = 0; it < 8; ++it) {
    int lin = it * 1024 + tid * 4;
    int mm = lin >> 8, d = lin & 255;
    float4 v = *(const float4*)(base + (size_t)(m0 + mm) * 256 + d);
    bs[mm][d] = v.x; bs[mm][d + 1] = v.y; bs[mm][d + 2] = v.z; bs[mm][d + 3] = v.w;
  }
  __syncthreads();
  const int ml = tid & 31, dg = tid >> 5;
  const float ac = adjcol[b * N_NODES + m0 + ml];
  const float* w1l = W1 + 255 * 256;
#pragma unroll 4
  for (int dd = 0; dd < 32; ++dd) {
    int d = dg * 32 + dd;
    float v = bs[ml][d] + b1[d] + ac * w1l[d];
    v = fmaxf(v, 0.f);
    Ht[(size_t)(b * 256 + d) * N_NODES + m0 + ml] = f2bf(v);
  }
}

// ---------------------------------------------------------------- out = Mcat@W2 + b2, fused layernorm -> holo fp32
// Mcat now bf16 (gemm2 emits f2bf of the same fp32 acc this kernel used to round).
__global__ __launch_bounds__(256)
void gemm3_ln(const unsigned short* __restrict__ Mcat, const unsigned short* __restrict__ W2t,
              const float* __restrict__ b2, const float* __restrict__ gamma,
              const float* __restrict__ beta, float* __restrict__ holo)
{
  const int tid  = threadIdx.x;
  const int w    = tid >> 6, lane = tid & 63;
  const int lhi  = lane >> 4, llo = lane & 15;
  const int n0   = blockIdx.x * 64;
  const int b    = blockIdx.y;
  const int row0 = n0 + w * 16;

  f32x4 acc[16];
  const f32x4 z = {0.f, 0.f, 0.f, 0.f};
#pragma unroll
  for (int j = 0; j < 16; ++j) acc[j] = z;

  const unsigned short* arow = Mcat + (size_t)(row0 + llo) * 2048 + b * 256;
#pragma unroll
  for (int k0 = 0; k0 < 256; k0 += 32) {
    const short8 fa = *(const short8*)&arow[k0 + lhi * 8];
#pragma unroll
    for (int j = 0; j < 16; ++j) {
      const short8 fb = *(const short8*)&W2t[(size_t)(j * 16 + llo) * 256 + k0 + lhi * 8];
      acc[j] = mfma16(fa, fb, acc[j]);
    }
  }
  float b2v[16];
#pragma unroll
  for (int j = 0; j < 16; ++j) b2v[j] = b2[j * 16 + llo];

  float mu[4], rs[4];
#pragma unroll
  for (int i = 0; i < 4; ++i) {
    float s = 0.f;
#pragma unroll
    for (int j = 0; j < 16; ++j) s += acc[j][i] + b2v[j];
    s += __shfl_xor(s, 1); s += __shfl_xor(s, 2);
    s += __shfl_xor(s, 4); s += __shfl_xor(s, 8);
    mu[i] = s * (1.f / 256.f);
  }
#pragma unroll
  for (int i = 0; i < 4; ++i) {
    float q = 0.f;
#pragma unroll
    for (int j = 0; j < 16; ++j) { float d = acc[j][i] + b2v[j] - mu[i]; q += d * d; }
    q += __shfl_xor(q, 1); q += __shfl_xor(q, 2);
    q += __shfl_xor(q, 4); q += __shfl_xor(q, 8);
    rs[i] = rsqrtf(q * (1.f / 256.f) + 1e-5f);
  }
  float* hb = holo + ((size_t)b * N_NODES + row0 + lhi * 4) * 256 + llo;
#pragma unroll
  for (int j = 0; j < 16; ++j) {
    const float gv = gamma[j * 16 + llo];
    const float bt = beta[j * 16 + llo];
#pragma unroll
    for (int i = 0; i < 4; ++i) {
      float x = acc[j][i] + b2v[j];
      hb[(size_t)i * 256 + j * 16] = (x - mu[i]) * rs[i] * gv + bt;
    }
  }
}

// ---------------------------------------------------------------- gather + product + group mean
__global__ __launch_bounds__(256)
void gather_k(const float* __restrict__ holo, const int* __restrict__ tc,
              const int* __restrict__ gidx, float* __restrict__ out)
{
  const int t = blockIdx.x;
  const int d = threadIdx.x;
  const int i = tc[t];
  const int j = tc[NT + t];
  float a0 = 0.f, a1 = 0.f, a2 = 0.f, a3 = 0.f;
  float c0 = 0.f, c1 = 0.f, c2 = 0.f, c3 = 0.f;
#pragma unroll
  for (int b = 0; b < NB; ++b) {
    const int g = gidx[b];
    const float p = holo[((size_t)b * N_NODES + i) * 256 + d] *
                    holo[((size_t)b * N_NODES + j) * 256 + d];
    a0 += (g == 0) ? p : 0.f;  c0 += (g == 0) ? 1.f : 0.f;
    a1 += (g == 1) ? p : 0.f;  c1 += (g == 1) ? 1.f : 0.f;
    a2 += (g == 2) ? p : 0.f;  c2 += (g == 2) ? 1.f : 0.f;
    a3 += (g == 3) ? p : 0.f;  c3 += (g == 3) ? 1.f : 0.f;
  }
  float* ob = out + (size_t)t * 1024 + d;
  ob[0]   = a0 / fmaxf(c0, 1.f);
  ob[256] = a1 / fmaxf(c1, 1.f);
  ob[512] = a2 / fmaxf(c2, 1.f);
  ob[768] = a3 / fmaxf(c3, 1.f);
}

// ----------------------------------------------------------------
extern "C" void kernel_launch(void* const* d_in, const int* in_sizes, int n_in,
                              void* d_out, int out_size, void* d_ws, size_t ws_size,
                              hipStream_t stream)
{
  const float* X     = (const float*)d_in[0];
  const float* adj   = (const float*)d_in[1];
  const float* W1    = (const float*)d_in[2];
  const float* b1    = (const float*)d_in[3];
  const float* W2    = (const float*)d_in[4];
  const float* b2    = (const float*)d_in[5];
  const float* gamma = (const float*)d_in[6];
  const float* beta  = (const float*)d_in[7];
  const int*   tc    = (const int*)d_in[8];
  const int*   gidx  = (const int*)d_in[9];

  char* w = (char*)d_ws;
  size_t off = 0;
  unsigned short* adjbf = (unsigned short*)(w + off);            // 32 MB, dead after gemm2
  float*          holo  = (float*)(w + off);  off += 33554432;   // reuses adjbf region
  unsigned short* Ht    = (unsigned short*)(w + off); off += 16777216;
  unsigned short* Mcat  = (unsigned short*)(w + off); off += 16777216;  // bf16 now
  float*          basep = (float*)(w + off);  off += 16777216;   // 4 K-split partials
  float*          base  = (float*)(w + off);  off += 4194304;
  unsigned short* Yt    = (unsigned short*)(w + off); off += 2097152;
  float*          deg   = (float*)(w + off);  off += 16384;
  int*            brk   = (int*)(w + off);    off += 256;
  float*          adjcol= (float*)(w + off);  off += 131072;
  unsigned short* W2t   = (unsigned short*)(w + off); off += 131072;
  float* out = (float*)d_out;

  deg_cvt     <<<N_NODES, 256, 0, stream>>>(adj, adjbf, deg);
  topk_kernel <<<1, 256, 0, stream>>>(deg, brk);
  extract_cols<<<N_NODES / 256, 256, 0, stream>>>(adj, brk, adjcol);
  gemm0       <<<N_NODES / G0R, 256, 0, stream>>>(X, W1, Yt);
  w2t_kernel  <<<256, 256, 0, stream>>>(W2, W2t);
  gemm_bt<64, 64, 64, 2, 2, false><<<dim3(N_NODES / 64, 256 / 64, 4), 256, 0, stream>>>(
      adjbf, Yt, basep, N_NODES, 256, N_NODES);
  reduce4     <<<N_NODES * 256 / 4 / 256, 256, 0, stream>>>(basep, base);
  h_kernel    <<<dim3(N_NODES / 32, NB), 256, 0, stream>>>(base, adjcol, b1, W1, Ht);
  gemm_bt<128, 128, 64, 4, 4, true><<<dim3(N_NODES / 128, 2048 / 128, 1), 256, 0, stream>>>(
      adjbf, Ht, Mcat, N_NODES, 2048, N_NODES);
  gemm3_ln    <<<dim3(N_NODES / 64, NB), 256, 0, stream>>>(Mcat, W2t, b2, gamma, beta, holo);
  gather_k    <<<NT, 256, 0, stream>>>(holo, tc, gidx, out);
}

// Round 10
// 362.559 us; speedup vs baseline: 1.5831x; 1.0338x over previous
//
#include <hip/hip_runtime.h>
#include <hip/hip_bf16.h>

#define N_NODES 4096
#define FEAT    255
#define NB      8
#define NT      16384
#define NG      4

typedef __attribute__((ext_vector_type(8))) short          short8;
typedef __attribute__((ext_vector_type(8))) __bf16         bf16x8;
typedef __attribute__((ext_vector_type(4))) float          f32x4;
typedef __attribute__((ext_vector_type(4))) unsigned short ushort4v;

__device__ __forceinline__ unsigned short f2bf(float f) {
  unsigned int u = __builtin_bit_cast(unsigned int, f);
  u += 0x7fffu + ((u >> 16) & 1u);           // RNE (inputs are finite)
  return (unsigned short)(u >> 16);
}

__device__ __forceinline__ f32x4 mfma16(short8 a, short8 b, f32x4 c) {
  return __builtin_amdgcn_mfma_f32_16x16x32_bf16(
      __builtin_bit_cast(bf16x8, a), __builtin_bit_cast(bf16x8, b), c, 0, 0, 0);
}

// async global->LDS, 16B per lane; lds dest must be wave-uniform base (HW adds lane*16)
__device__ __forceinline__ void gload_lds16(const void* g, void* l) {
  __builtin_amdgcn_global_load_lds((__attribute__((address_space(1))) void*)(void*)g,
                                   (__attribute__((address_space(3))) void*)l, 16, 0, 0);
}

// ---------------------------------------------------------------- deg + bf16 cvt
__global__ __launch_bounds__(256)
void deg_cvt(const float* __restrict__ adj, unsigned short* __restrict__ adjbf,
             float* __restrict__ deg)
{
  const int n = blockIdx.x;
  const int tid = threadIdx.x;
  const float* row = adj + (size_t)n * N_NODES;
  float s = 0.f;
#pragma unroll
  for (int it = 0; it < 4; ++it) {
    int idx = it * 1024 + tid * 4;
    float4 v = *(const float4*)(row + idx);
    s += (v.x + v.y) + (v.z + v.w);
    ushort4v o;
    o[0] = f2bf(v.x); o[1] = f2bf(v.y); o[2] = f2bf(v.z); o[3] = f2bf(v.w);
    *(ushort4v*)(adjbf + (size_t)n * N_NODES + idx) = o;
  }
#pragma unroll
  for (int off = 32; off > 0; off >>= 1) s += __shfl_xor(s, off);
  __shared__ float ws4[4];
  if ((tid & 63) == 0) ws4[tid >> 6] = s;
  __syncthreads();
  if (tid == 0) deg[n] = (ws4[0] + ws4[1]) + (ws4[2] + ws4[3]);
}

// ---------------------------------------------------------------- top-8 (tie: lower idx)
__global__ __launch_bounds__(256)
void topk_kernel(const float* __restrict__ deg, int* __restrict__ brk)
{
  __shared__ float v[N_NODES];
  __shared__ float wv[4];
  __shared__ int   wi[4];
  const int tid = threadIdx.x;
  for (int i = tid; i < N_NODES; i += 256) v[i] = deg[i];
  __syncthreads();
  for (int it = 0; it < NB; ++it) {
    float best = -1e30f; int bidx = 0x7fffffff;
#pragma unroll
    for (int k = 0; k < N_NODES / 256; ++k) {
      int i = k * 256 + tid;
      float x = v[i];
      if (x > best) { best = x; bidx = i; }   // ascending scan: ties keep lower idx
    }
#pragma unroll
    for (int off = 1; off < 64; off <<= 1) {
      float ov = __shfl_xor(best, off);
      int   oi = __shfl_xor(bidx, off);
      if (ov > best || (ov == best && oi < bidx)) { best = ov; bidx = oi; }
    }
    if ((tid & 63) == 0) { wv[tid >> 6] = best; wi[tid >> 6] = bidx; }
    __syncthreads();
    if (tid == 0) {
      float bb = wv[0]; int bbi = wi[0];
#pragma unroll
      for (int k = 1; k < 4; ++k)
        if (wv[k] > bb || (wv[k] == bb && wi[k] < bbi)) { bb = wv[k]; bbi = wi[k]; }
      brk[it] = bbi;
      v[bbi] = -1e30f;
    }
    __syncthreads();
  }
}

// ---------------------------------------------------------------- fused prep: gemm0 | extract_cols | w2t
// blocks [0,512): Yt[d][m] = bf16((X @ W1[:255])^T), 8 m-rows/block
// blocks [512,528): adjcol[b][n] = adj[n][brk[b]]
// blocks [528,784): W2t[d][k] = bf16(W2[k][d])
#define G0R 8
__global__ __launch_bounds__(256)
void prep_kernel(const float* __restrict__ X, const float* __restrict__ W1,
                 const float* __restrict__ adj, const int* __restrict__ brk,
                 const float* __restrict__ W2,
                 unsigned short* __restrict__ Yt, float* __restrict__ adjcol,
                 unsigned short* __restrict__ W2t)
{
  __shared__ float xr[G0R][256];
  const int bid = blockIdx.x;
  const int tid = threadIdx.x;
  if (bid < 512) {
    const int m0 = bid * G0R;
    for (int i = tid; i < G0R * FEAT; i += 256) {
      int r = i / FEAT, c = i - r * FEAT;
      xr[r][c] = X[(size_t)(m0 + r) * FEAT + c];
    }
    __syncthreads();
    const int d = tid;
    float s[G0R] = {};
    for (int fq = 0; fq < 252; fq += 4) {
      float w0 = W1[(fq + 0) * 256 + d];
      float w1 = W1[(fq + 1) * 256 + d];
      float w2 = W1[(fq + 2) * 256 + d];
      float w3 = W1[(fq + 3) * 256 + d];
#pragma unroll
      for (int r = 0; r < G0R; ++r) {
        float4 x4 = *(const float4*)&xr[r][fq];
        s[r] = fmaf(x4.x, w0, s[r]);
        s[r] = fmaf(x4.y, w1, s[r]);
        s[r] = fmaf(x4.z, w2, s[r]);
        s[r] = fmaf(x4.w, w3, s[r]);
      }
    }
    for (int f = 252; f < FEAT; ++f) {
      float wv = W1[f * 256 + d];
#pragma unroll
      for (int r = 0; r < G0R; ++r) s[r] = fmaf(xr[r][f], wv, s[r]);
    }
#pragma unroll
    for (int r = 0; r < G0R; ++r)
      Yt[(size_t)d * N_NODES + m0 + r] = f2bf(s[r]);
  } else if (bid < 528) {
    const int n = (bid - 512) * 256 + tid;
#pragma unroll
    for (int b = 0; b < NB; ++b)
      adjcol[b * N_NODES + n] = adj[(size_t)n * N_NODES + brk[b]];
  } else {
    const int k = bid - 528, d = tid;
    W2t[(size_t)d * 256 + k] = f2bf(W2[(size_t)k * 256 + d]);
  }
}

// ---------------------------------------------------------------- bf16 GEMM, C = A @ Bt^T
// A: [M][K] bf16 row-major, Bt: [N][K] bf16 row-major.
// m97 structure + T2 XOR-swizzle (verified r7: BANK_CONFLICT 2.5e7 -> 0).
// OUTBF: emit bf16 C. K-split via blockIdx.z writes C + z*M*Nn.
// Wave grid: 2x2 waves; wave tile (FM*16) x (FN*16); BM=2*FM*16, BN=2*FN*16.
template<int BM, int BN, int BK, int FM, int FN, bool OUTBF>
__global__ __launch_bounds__(256)
void gemm_bt(const unsigned short* __restrict__ A, const unsigned short* __restrict__ Bt,
             void* __restrict__ Cv, int M, int Nn, int K)
{
  static_assert(BK == 64, "staging/swizzle math assumes BK=64 (128 B = 8 chunks/row)");
  static_assert(BM == 2 * FM * 16 && BN == 2 * FN * 16, "2x2 wave grid");
  __shared__ unsigned short As[BM * BK];
  __shared__ unsigned short Bs[BN * BK];
  const int tid  = threadIdx.x;
  const int lane = tid & 63;
  const int w    = tid >> 6;
  const int wr   = w >> 1, wc = w & 1;
  const int lhi  = lane >> 4, llo = lane & 15;
  const int brow = blockIdx.x * BM;
  const int bcol = blockIdx.y * BN;
  const int Kper = K / gridDim.z;
  const int kbeg = blockIdx.z * Kper;

  f32x4 acc[FM][FN];
  const f32x4 z = {0.f, 0.f, 0.f, 0.f};
#pragma unroll
  for (int m = 0; m < FM; ++m)
#pragma unroll
    for (int n = 0; n < FN; ++n) acc[m][n] = z;

  for (int k0 = kbeg; k0 < kbeg + Kper; k0 += BK) {
    __syncthreads();
#pragma unroll
    for (int i = 0; i < (BM * BK * 2) / 4096; ++i) {
      int byte = i * 4096 + tid * 16;            // linear LDS byte offset
      int row  = byte >> 7;                      // 128 B per row
      int sc   = ((byte >> 4) & 7) ^ (row & 7);  // swizzled source chunk
      gload_lds16(A + (size_t)(brow + row) * K + k0 + sc * 8,
                  As + ((i * 4096 + w * 1024) >> 1));
    }
#pragma unroll
    for (int i = 0; i < (BN * BK * 2) / 4096; ++i) {
      int byte = i * 4096 + tid * 16;
      int row  = byte >> 7;
      int sc   = ((byte >> 4) & 7) ^ (row & 7);
      gload_lds16(Bt + (size_t)(bcol + row) * K + k0 + sc * 8,
                  Bs + ((i * 4096 + w * 1024) >> 1));
    }
    __syncthreads();
#pragma unroll
    for (int kk = 0; kk < BK; kk += 32) {
      short8 fa[FM], fb[FN];
#pragma unroll
      for (int m = 0; m < FM; ++m) {
        const int ar = wr * FM * 16 + m * 16 + llo;
        const int ac = ((kk >> 3) + lhi) ^ (ar & 7);   // same involution on read
        fa[m] = *(const short8*)&As[ar * BK + ac * 8];
      }
#pragma unroll
      for (int n = 0; n < FN; ++n) {
        const int br = wc * FN * 16 + n * 16 + llo;
        const int bc = ((kk >> 3) + lhi) ^ (br & 7);
        fb[n] = *(const short8*)&Bs[br * BK + bc * 8];
      }
#pragma unroll
      for (int m = 0; m < FM; ++m)
#pragma unroll
        for (int n = 0; n < FN; ++n)
          acc[m][n] = mfma16(fa[m], fb[n], acc[m][n]);
    }
  }
#pragma unroll
  for (int m = 0; m < FM; ++m)
#pragma unroll
    for (int n = 0; n < FN; ++n) {
      const int r = brow + wr * FM * 16 + m * 16 + lhi * 4;
      const int c = bcol + wc * FN * 16 + n * 16 + llo;
      if constexpr (OUTBF) {
        unsigned short* cp = (unsigned short*)Cv + (size_t)blockIdx.z * M * Nn
                             + (size_t)r * Nn + c;
#pragma unroll
        for (int i = 0; i < 4; ++i) cp[(size_t)i * Nn] = f2bf(acc[m][n][i]);
      } else {
        float* cp = (float*)Cv + (size_t)blockIdx.z * M * Nn + (size_t)r * Nn + c;
#pragma unroll
        for (int i = 0; i < 4; ++i) cp[(size_t)i * Nn] = acc[m][n][i];
      }
    }
}

// ---------------------------------------------------------------- Ht[b*256+d][m] = bf16(relu(sum4(basep)+b1+adjcol*W1last))
// reduce4 fused into the LDS staging read (partials are L2/L3-resident).
__global__ __launch_bounds__(256)
void h_kernel(const float* __restrict__ basep, const float* __restrict__ adjcol,
              const float* __restrict__ b1, const float* __restrict__ W1,
              unsigned short* __restrict__ Ht)
{
  __shared__ float bs[32][261];              // pad 261: conflict-free column reads
  const int tid = threadIdx.x;
  const int m0  = blockIdx.x * 32;
  const int b   = blockIdx.y;
#pragma unroll
  for (int it = 0; it < 8; ++it) {
    int lin = it * 1024 + tid * 4;
    int mm = lin >> 8, d = lin & 255;
    const float* p = basep + (size_t)(m0 + mm) * 256 + d;
    float4 v0 = *(const float4*)(p);
    float4 v1 = *(const float4*)(p + 1048576);
    float4 v2 = *(const float4*)(p + 2097152);
    float4 v3 = *(const float4*)(p + 3145728);
    bs[mm][d]     = ((v0.x + v1.x) + v2.x) + v3.x;
    bs[mm][d + 1] = ((v0.y + v1.y) + v2.y) + v3.y;
    bs[mm][d + 2] = ((v0.z + v1.z) + v2.z) + v3.z;
    bs[mm][d + 3] = ((v0.w + v1.w) + v2.w) + v3.w;
  }
  __syncthreads();
  const int ml = tid & 31, dg = tid >> 5;
  const float ac = adjcol[b * N_NODES + m0 + ml];
  const float* w1l = W1 + 255 * 256;
#pragma unroll 4
  for (int dd = 0; dd < 32; ++dd) {
    int d = dg * 32 + dd;
    float v = bs[ml][d] + b1[d] + ac * w1l[d];
    v = fmaxf(v, 0.f);
    Ht[(size_t)(b * 256 + d) * N_NODES + m0 + ml] = f2bf(v);
  }
}

// ---------------------------------------------------------------- out = Mcat@W2 + b2, fused layernorm -> holo fp32
// holo layout [n][b][d]: each tuple's 8 b-rows are contiguous for gather_k.
__global__ __launch_bounds__(256)
void gemm3_ln(const unsigned short* __restrict__ Mcat, const unsigned short* __restrict__ W2t,
              const float* __restrict__ b2, const float* __restrict__ gamma,
              const float* __restrict__ beta, float* __restrict__ holo)
{
  const int tid  = threadIdx.x;
  const int w    = tid >> 6, lane = tid & 63;
  const int lhi  = lane >> 4, llo = lane & 15;
  const int n0   = blockIdx.x * 64;
  const int b    = blockIdx.y;
  const int row0 = n0 + w * 16;

  f32x4 acc[16];
  const f32x4 z = {0.f, 0.f, 0.f, 0.f};
#pragma unroll
  for (int j = 0; j < 16; ++j) acc[j] = z;

  const unsigned short* arow = Mcat + (size_t)(row0 + llo) * 2048 + b * 256;
#pragma unroll
  for (int k0 = 0; k0 < 256; k0 += 32) {
    const short8 fa = *(const short8*)&arow[k0 + lhi * 8];
#pragma unroll
    for (int j = 0; j < 16; ++j) {
      const short8 fb = *(const short8*)&W2t[(size_t)(j * 16 + llo) * 256 + k0 + lhi * 8];
      acc[j] = mfma16(fa, fb, acc[j]);
    }
  }
  float b2v[16];
#pragma unroll
  for (int j = 0; j < 16; ++j) b2v[j] = b2[j * 16 + llo];

  float mu[4], rs[4];
#pragma unroll
  for (int i = 0; i < 4; ++i) {
    float s = 0.f;
#pragma unroll
    for (int j = 0; j < 16; ++j) s += acc[j][i] + b2v[j];
    s += __shfl_xor(s, 1); s += __shfl_xor(s, 2);
    s += __shfl_xor(s, 4); s += __shfl_xor(s, 8);
    mu[i] = s * (1.f / 256.f);
  }
#pragma unroll
  for (int i = 0; i < 4; ++i) {
    float q = 0.f;
#pragma unroll
    for (int j = 0; j < 16; ++j) { float d = acc[j][i] + b2v[j] - mu[i]; q += d * d; }
    q += __shfl_xor(q, 1); q += __shfl_xor(q, 2);
    q += __shfl_xor(q, 4); q += __shfl_xor(q, 8);
    rs[i] = rsqrtf(q * (1.f / 256.f) + 1e-5f);
  }
  // holo[(n*8 + b)*256 + d]
  float* hb = holo + ((size_t)(row0 + lhi * 4) * 8 + b) * 256 + llo;
#pragma unroll
  for (int j = 0; j < 16; ++j) {
    const float gv = gamma[j * 16 + llo];
    const float bt = beta[j * 16 + llo];
#pragma unroll
    for (int i = 0; i < 4; ++i) {
      float x = acc[j][i] + b2v[j];
      hb[(size_t)i * 2048 + j * 16] = (x - mu[i]) * rs[i] * gv + bt;
    }
  }
}

// ---------------------------------------------------------------- gather + product + group mean
// holo [n][b][d]: the 16 rows per tuple are 2 contiguous 8KB chunks.
__global__ __launch_bounds__(256)
void gather_k(const float* __restrict__ holo, const int* __restrict__ tc,
              const int* __restrict__ gidx, float* __restrict__ out)
{
  const int t = blockIdx.x;
  const int d = threadIdx.x;
  const int i = tc[t];
  const int j = tc[NT + t];
  const float* hi = holo + (size_t)i * 2048 + d;
  const float* hj = holo + (size_t)j * 2048 + d;
  float a0 = 0.f, a1 = 0.f, a2 = 0.f, a3 = 0.f;
  float c0 = 0.f, c1 = 0.f, c2 = 0.f, c3 = 0.f;
#pragma unroll
  for (int b = 0; b < NB; ++b) {
    const int g = gidx[b];
    const float p = hi[b * 256] * hj[b * 256];
    a0 += (g == 0) ? p : 0.f;  c0 += (g == 0) ? 1.f : 0.f;
    a1 += (g == 1) ? p : 0.f;  c1 += (g == 1) ? 1.f : 0.f;
    a2 += (g == 2) ? p : 0.f;  c2 += (g == 2) ? 1.f : 0.f;
    a3 += (g == 3) ? p : 0.f;  c3 += (g == 3) ? 1.f : 0.f;
  }
  float* ob = out + (size_t)t * 1024 + d;
  ob[0]   = a0 / fmaxf(c0, 1.f);
  ob[256] = a1 / fmaxf(c1, 1.f);
  ob[512] = a2 / fmaxf(c2, 1.f);
  ob[768] = a3 / fmaxf(c3, 1.f);
}

// ----------------------------------------------------------------
extern "C" void kernel_launch(void* const* d_in, const int* in_sizes, int n_in,
                              void* d_out, int out_size, void* d_ws, size_t ws_size,
                              hipStream_t stream)
{
  const float* X     = (const float*)d_in[0];
  const float* adj   = (const float*)d_in[1];
  const float* W1    = (const float*)d_in[2];
  const float* b1    = (const float*)d_in[3];
  const float* W2    = (const float*)d_in[4];
  const float* b2    = (const float*)d_in[5];
  const float* gamma = (const float*)d_in[6];
  const float* beta  = (const float*)d_in[7];
  const int*   tc    = (const int*)d_in[8];
  const int*   gidx  = (const int*)d_in[9];

  char* w = (char*)d_ws;
  size_t off = 0;
  unsigned short* adjbf = (unsigned short*)(w + off);            // 32 MB, dead after gemm2
  float*          holo  = (float*)(w + off);  off += 33554432;   // reuses adjbf region
  unsigned short* Ht    = (unsigned short*)(w + off); off += 16777216;
  unsigned short* Mcat  = (unsigned short*)(w + off); off += 16777216;  // bf16
  float*          basep = (float*)(w + off);  off += 16777216;   // 4 K-split partials
  unsigned short* Yt    = (unsigned short*)(w + off); off += 2097152;
  float*          deg   = (float*)(w + off);  off += 16384;
  int*            brk   = (int*)(w + off);    off += 256;
  float*          adjcol= (float*)(w + off);  off += 131072;
  unsigned short* W2t   = (unsigned short*)(w + off); off += 131072;
  float* out = (float*)d_out;

  deg_cvt     <<<N_NODES, 256, 0, stream>>>(adj, adjbf, deg);
  topk_kernel <<<1, 256, 0, stream>>>(deg, brk);
  prep_kernel <<<784, 256, 0, stream>>>(X, W1, adj, brk, W2, Yt, adjcol, W2t);
  gemm_bt<64, 128, 64, 2, 4, false><<<dim3(N_NODES / 64, 256 / 128, 4), 256, 0, stream>>>(
      adjbf, Yt, basep, N_NODES, 256, N_NODES);
  h_kernel    <<<dim3(N_NODES / 32, NB), 256, 0, stream>>>(basep, adjcol, b1, W1, Ht);
  gemm_bt<128, 128, 64, 4, 4, true><<<dim3(N_NODES / 128, 2048 / 128, 1), 256, 0, stream>>>(
      adjbf, Ht, Mcat, N_NODES, 2048, N_NODES);
  gemm3_ln    <<<dim3(N_NODES / 64, NB), 256, 0, stream>>>(Mcat, W2t, b2, gamma, beta, holo);
  gather_k    <<<NT, 256, 0, stream>>>(holo, tc, gidx, out);
}